// Round 1
// baseline (494.501 us; speedup 1.0000x reference)
//
#include <hip/hip_runtime.h>

// FSP loss: loss = mean_{b,i,j} (( (S2 S1^T - T2 T1^T)/T )^2 )
// B=16, C=512, T=4096, fp32 inputs, scalar fp32 output.
//
// K1: per-pair 128x128-tile GEMM via bf16 MFMA (RTN conversion), unscaled
//     partial sums (over t) to ws: ws[pair][b][i][j], pair1 sign-folded (-t2).
// K2: sum of (ws0+ws1)^2 -> 512 block partials.
// K3: final reduce + scale by 1/(T^2 * B * C * C).

using f32x4  = __attribute__((ext_vector_type(4))) float;
using bf16x8 = __attribute__((ext_vector_type(8))) __bf16;

constexpr int FSP_T = 4096;
constexpr int FSP_C = 512;
constexpr int FSP_B = 16;

// round-to-nearest-even f32->bf16, packed pair, with sign-fold mask
__device__ __forceinline__ unsigned pack2bf(float x, float y, unsigned sgn) {
    unsigned ux = __float_as_uint(x) ^ sgn;
    unsigned uy = __float_as_uint(y) ^ sgn;
    ux += 0x7fffu + ((ux >> 16) & 1u);
    uy += 0x7fffu + ((uy >> 16) & 1u);
    return (ux >> 16) | (uy & 0xffff0000u);
}

__global__ __launch_bounds__(512, 4) void fsp_gemm_kernel(
    const float* __restrict__ s1, const float* __restrict__ s2,
    const float* __restrict__ t1, const float* __restrict__ t2,
    float* __restrict__ ws)
{
    // double-buffered bf16 tiles: [buf][A 128x64 | B 128x64], 32 KB per buffer
    __shared__ __align__(16) unsigned char lds[65536];

    // XCD-aware swizzle: XCD x gets works x*64..x*64+63 -> batches 2x,2x+1
    const int bid  = blockIdx.x;
    const int work = ((bid & 7) << 6) | (bid >> 3);
    const int b      = work >> 5;       // 2 pairs * 16 tiles per batch
    const int rem    = work & 31;
    const int pairid = rem >> 4;        // 0 = (s2,s1), 1 = (t2,t1)
    const int tile   = rem & 15;
    const int i0 = (tile >> 2) << 7;
    const int j0 = (tile & 3) << 7;

    const float* __restrict__ top = pairid ? t2 : s2;   // A source (output rows)
    const float* __restrict__ bot = pairid ? t1 : s1;   // B source (output cols)
    const unsigned sgn = pairid ? 0x80000000u : 0u;     // fold -1 into t2

    const int tid   = threadIdx.x;
    const int c4    = tid & 15;    // float4 column slot within BK=64 (16 slots)
    const int rbase = tid >> 4;    // 0..31; rows rbase + 32*s, s=0..3

    const f32x4* __restrict__ gA =
        reinterpret_cast<const f32x4*>(top) + ((size_t)b * FSP_C + i0) * (FSP_T / 4);
    const f32x4* __restrict__ gB =
        reinterpret_cast<const f32x4*>(bot) + ((size_t)b * FSP_C + j0) * (FSP_T / 4);

    // LDS write byte offsets (XOR-swizzled 16B chunks: chunk ^= row&7)
    int wrA[4], wrB[4];
#pragma unroll
    for (int s = 0; s < 4; ++s) {
        int row = rbase + (s << 5);
        int off = row * 128 + (((c4 >> 1) ^ (row & 7)) << 4) + ((c4 & 1) << 3);
        wrA[s] = off;
        wrB[s] = off + 16384;
    }

    const int lane = tid & 63;
    const int wid  = tid >> 6;
    const int wm   = wid >> 2;   // 0..1 : 64-row block
    const int wn   = wid & 3;    // 0..3 : 32-col block
    const int l15  = lane & 15;
    const int lg   = lane >> 4;  // 0..3
    const int cxor = l15 & 7;    // (row&7) for all frag rows (16-aligned bases)

    int aoff[4], boff[2];
#pragma unroll
    for (int m = 0; m < 4; ++m) aoff[m] = ((wm << 6) + (m << 4) + l15) * 128;
#pragma unroll
    for (int n = 0; n < 2; ++n) boff[n] = 16384 + ((wn << 5) + (n << 4) + l15) * 128;

    f32x4 acc[4][2];
#pragma unroll
    for (int m = 0; m < 4; ++m)
#pragma unroll
        for (int n = 0; n < 2; ++n)
            acc[m][n] = f32x4{0.f, 0.f, 0.f, 0.f};

    f32x4 rA[4], rB[4];

    auto load_step = [&](int ks) {
        const int kso = ks << 4;  // ks*64/4 float4s
#pragma unroll
        for (int s = 0; s < 4; ++s) {
            rA[s] = gA[(size_t)(rbase + (s << 5)) * (FSP_T / 4) + kso + c4];
            rB[s] = gB[(size_t)(rbase + (s << 5)) * (FSP_T / 4) + kso + c4];
        }
    };

    auto cvt_write = [&](int buf) {
        const int bufo = buf << 15;
#pragma unroll
        for (int s = 0; s < 4; ++s) {
            uint2 pa, pb;
            pa.x = pack2bf(rA[s][0], rA[s][1], sgn);
            pa.y = pack2bf(rA[s][2], rA[s][3], sgn);
            pb.x = pack2bf(rB[s][0], rB[s][1], 0u);
            pb.y = pack2bf(rB[s][2], rB[s][3], 0u);
            *reinterpret_cast<uint2*>(lds + bufo + wrA[s]) = pa;
            *reinterpret_cast<uint2*>(lds + bufo + wrB[s]) = pb;
        }
    };

    auto compute = [&](int buf) {
        const int bufo = buf << 15;
#pragma unroll
        for (int kk = 0; kk < 2; ++kk) {
            const int coff = ((((kk << 2) | lg) ^ cxor) << 4);
            bf16x8 a[4], bb[2];
#pragma unroll
            for (int m = 0; m < 4; ++m)
                a[m] = *reinterpret_cast<const bf16x8*>(lds + bufo + aoff[m] + coff);
#pragma unroll
            for (int n = 0; n < 2; ++n)
                bb[n] = *reinterpret_cast<const bf16x8*>(lds + bufo + boff[n] + coff);
#pragma unroll
            for (int m = 0; m < 4; ++m)
#pragma unroll
                for (int n = 0; n < 2; ++n)
                    acc[m][n] = __builtin_amdgcn_mfma_f32_16x16x32_bf16(
                        a[m], bb[n], acc[m][n], 0, 0, 0);
        }
    };

    load_step(0);
    cvt_write(0);
    __syncthreads();

    for (int ks = 0; ks < FSP_T / 64; ++ks) {
        if (ks < FSP_T / 64 - 1) load_step(ks + 1);   // overlap HBM with MFMA
        compute(ks & 1);
        if (ks < FSP_T / 64 - 1) {
            cvt_write((ks + 1) & 1);   // safe: last reader of this buffer passed
            __syncthreads();           // the barrier at end of previous iter
        }
    }

    // epilogue: unscaled partial sums (sign already folded for pair 1)
    float* __restrict__ wsP = ws + ((size_t)pairid * FSP_B + b) * (FSP_C * FSP_C);
#pragma unroll
    for (int m = 0; m < 4; ++m)
#pragma unroll
        for (int n = 0; n < 2; ++n)
#pragma unroll
            for (int r = 0; r < 4; ++r) {
                const int gr = i0 + (wm << 6) + (m << 4) + (lg << 2) + r;
                const int gc = j0 + (wn << 5) + (n << 4) + l15;
                wsP[(size_t)gr * FSP_C + gc] = acc[m][n][r];
            }
}

__global__ __launch_bounds__(256) void fsp_sq_kernel(
    const float* __restrict__ ws, float* __restrict__ partials)
{
    constexpr int NVEC = (FSP_B * FSP_C * FSP_C) / 4;  // 1048576
    const f32x4* __restrict__ p0 = reinterpret_cast<const f32x4*>(ws);
    const f32x4* __restrict__ p1 = p0 + NVEC;
    const int gtid = blockIdx.x * 256 + threadIdx.x;

    float acc = 0.f;
    for (int v = gtid; v < NVEC; v += 512 * 256) {
        f32x4 a = p0[v];
        f32x4 c = p1[v];
#pragma unroll
        for (int e = 0; e < 4; ++e) {
            float d = a[e] + c[e];
            acc = fmaf(d, d, acc);
        }
    }
#pragma unroll
    for (int off = 32; off > 0; off >>= 1) acc += __shfl_down(acc, off);
    __shared__ float red[4];
    const int lane = threadIdx.x & 63, w = threadIdx.x >> 6;
    if (lane == 0) red[w] = acc;
    __syncthreads();
    if (threadIdx.x == 0) partials[blockIdx.x] = red[0] + red[1] + red[2] + red[3];
}

__global__ __launch_bounds__(256) void fsp_final_kernel(
    const float* __restrict__ partials, float* __restrict__ out)
{
    float v = partials[threadIdx.x] + partials[threadIdx.x + 256];
#pragma unroll
    for (int off = 32; off > 0; off >>= 1) v += __shfl_down(v, off);
    __shared__ float red[4];
    const int lane = threadIdx.x & 63, w = threadIdx.x >> 6;
    if (lane == 0) red[w] = v;
    __syncthreads();
    if (threadIdx.x == 0) {
        // loss = sum((p0+p1)^2) / (T^2 * B * C * C)
        const float SCALE = (float)(1.0 / (16777216.0 * 4194304.0));
        out[0] = (red[0] + red[1] + red[2] + red[3]) * SCALE;
    }
}

extern "C" void kernel_launch(void* const* d_in, const int* in_sizes, int n_in,
                              void* d_out, int out_size, void* d_ws, size_t ws_size,
                              hipStream_t stream) {
    const float* s1 = (const float*)d_in[0];
    const float* s2 = (const float*)d_in[1];
    const float* t1 = (const float*)d_in[2];
    const float* t2 = (const float*)d_in[3];
    float* ws = (float*)d_ws;                                   // 2*16*512*512 f32 = 33.55 MB
    float* partials = ws + (size_t)2 * FSP_B * FSP_C * FSP_C;   // +512 f32
    float* out = (float*)d_out;

    fsp_gemm_kernel<<<dim3(512), dim3(512), 0, stream>>>(s1, s2, t1, t2, ws);
    fsp_sq_kernel<<<dim3(512), dim3(256), 0, stream>>>(ws, partials);
    fsp_final_kernel<<<dim3(1), dim3(256), 0, stream>>>(partials, out);
}